// Round 1
// baseline (287.960 us; speedup 1.0000x reference)
//
#include <hip/hip_runtime.h>
#include <hip/hip_bf16.h>

// Problem constants (AttentionLayer: B=16, S=2048, D=512, H=64)
#define B_ 16
#define S_ 2048
#define D_ 512
#define H_ 64

typedef __attribute__((ext_vector_type(8))) short short8;   // 8 x bf16 (4 VGPRs)
typedef __attribute__((ext_vector_type(4))) float f32x4;    // MFMA accumulator

static __device__ __forceinline__ short f2bf(float f) {
  union { __hip_bfloat16 h; short s; } u;
  u.h = __float2bfloat16(f);   // RNE
  return u.s;
}

// XOR-swizzle (16B granules within a 128B row) to avoid LDS bank conflicts on
// the stride-128B A-fragment read pattern (G4: row-major D=64-bf16 tiles are a
// 16-way conflict without this).
static __device__ __forceinline__ int swz(int row, int byte_in_row) {
  int g = ((byte_in_row >> 4) ^ (row & 7)) & 7;
  return row * 128 + (g << 4) + (byte_in_row & 15);
}

// ---------------------------------------------------------------------------
// Kernel 0: transpose + convert weights to bf16.  Wt[n][k], n in [0,192):
//   n<64 -> Wq col n ; n<128 -> Wk col n-64 ; else Wv col n-128.
// Lets the GEMM B-fragment (lane reads W[k..k+7][ncol] = Wt[ncol][k..k+7])
// be one contiguous 16B load.
// ---------------------------------------------------------------------------
__global__ void prep_weights(const float* __restrict__ Wq,
                             const float* __restrict__ Wk,
                             const float* __restrict__ Wv,
                             short* __restrict__ Wt) {
  int n = blockIdx.x;                       // 0..191
  const float* src = (n < 64) ? Wq : (n < 128) ? Wk : Wv;
  int col = n & 63;
  for (int k = threadIdx.x; k < D_; k += 256)
    Wt[n * D_ + k] = f2bf(src[k * H_ + col]);
}

// ---------------------------------------------------------------------------
// Kernel 1: fused QKV projection.  C[32768x192] = in[32768x512] * W[512x192].
// Grid 512 blocks x 256 thr (4 waves).  Wave w owns rows [bid*64+w*16, +16),
// all 192 output cols (12 n-fragments), K-loop over 16 chunks of 32.
// A-fragments read fp32 straight from global (no reuse within block -> LDS
// would not reduce traffic) and convert to bf16 in-register.
// Outputs: Q,K bf16 row-major [B*S][64]; V transposed Vt[b][h][s] via LDS.
// ---------------------------------------------------------------------------
__global__ __launch_bounds__(256) void qkv_proj(
    const float* __restrict__ in, const short* __restrict__ Wt,
    const float* __restrict__ bq, const float* __restrict__ bk,
    const float* __restrict__ bv,
    short* __restrict__ Qb, short* __restrict__ Kb, short* __restrict__ Vt) {
  int tid = threadIdx.x;
  int w = tid >> 6, lane = tid & 63, lq = lane & 15, lg = lane >> 4;
  int rowbase = blockIdx.x * 64 + w * 16;
  size_t arow = (size_t)(rowbase + lq) * D_;

  f32x4 acc[12];
#pragma unroll
  for (int n = 0; n < 12; ++n) acc[n] = (f32x4){0.f, 0.f, 0.f, 0.f};

  for (int kk = 0; kk < 16; ++kk) {
    const float4* ap = reinterpret_cast<const float4*>(in + arow + kk * 32 + lg * 8);
    float4 a0 = ap[0], a1 = ap[1];
    short8 af;
    af[0] = f2bf(a0.x); af[1] = f2bf(a0.y); af[2] = f2bf(a0.z); af[3] = f2bf(a0.w);
    af[4] = f2bf(a1.x); af[5] = f2bf(a1.y); af[6] = f2bf(a1.z); af[7] = f2bf(a1.w);
#pragma unroll
    for (int n = 0; n < 12; ++n) {
      short8 bf = *reinterpret_cast<const short8*>(Wt + (n * 16 + lq) * D_ + kk * 32 + lg * 8);
      acc[n] = __builtin_amdgcn_mfma_f32_16x16x32_bf16(af, bf, acc[n], 0, 0, 0);
    }
  }

  // Epilogue.  D-frag: lane holds rows (lg*4+r), col n*16+lq.
  __shared__ short vtile[64][72];  // [h][s_local], +8 pad breaks conflicts
  int batch = (blockIdx.x * 64) >> 11;
  int s0 = (blockIdx.x * 64) & (S_ - 1);

#pragma unroll
  for (int n = 0; n < 4; ++n) {
    int h = n * 16 + lq;
    float bbq = bq[h], bbk = bk[h], bbv = bv[h];
#pragma unroll
    for (int r = 0; r < 4; ++r) {
      size_t row = (size_t)(rowbase + lg * 4 + r);
      Qb[row * H_ + h] = f2bf(acc[n][r] + bbq);
      Kb[row * H_ + h] = f2bf(acc[n + 4][r] + bbk);
      vtile[h][w * 16 + lg * 4 + r] = f2bf(acc[n + 8][r] + bbv);
    }
  }
  __syncthreads();
  // Coalesced transposed V store: thread -> (h = tid/4, 16 s-values).
  {
    int h = tid >> 2, sc = (tid & 3) * 16;
    short8* dst = reinterpret_cast<short8*>(Vt + ((size_t)batch * H_ + h) * S_ + s0 + sc);
    const short8* srcp = reinterpret_cast<const short8*>(&vtile[h][sc]);
    dst[0] = srcp[0];
    dst[1] = srcp[1];
  }
}

// ---------------------------------------------------------------------------
// Kernel 2: flash attention + mean pool.  Grid = B * (S/64) = 512 blocks,
// 4 waves x 16 q-rows.  Per 64-t tile: QK^T (8 MFMA) -> online softmax in
// fragments -> P to bf16 via swizzled LDS (per-wave private, no barrier)
// -> PV (8 MFMA).  End: /l, block-reduce rows, atomicAdd(out)/2048.
// ---------------------------------------------------------------------------
__global__ __launch_bounds__(256) void attn_kernel(
    const short* __restrict__ Qb, const short* __restrict__ Kb,
    const short* __restrict__ Vt, float* __restrict__ out) {
  int tid = threadIdx.x;
  int w = tid >> 6, lane = tid & 63, lq = lane & 15, lg = lane >> 4;
  int b = blockIdx.x >> 5, qt = blockIdx.x & 31;
  size_t boff = (size_t)b * (S_ * H_);
  int qrow = qt * 64 + w * 16;

  __shared__ char plds[4 * 2048];
  __shared__ float redbuf[4][64];
  char* pbase = plds + w * 2048;

  // Q fragments (held in registers for the whole kernel).
  short8 qa[2];
#pragma unroll
  for (int kk = 0; kk < 2; ++kk)
    qa[kk] = *reinterpret_cast<const short8*>(
        Qb + boff + (size_t)(qrow + lq) * H_ + kk * 32 + lg * 8);

  f32x4 o[4];
  float m[4], l[4];
#pragma unroll
  for (int f = 0; f < 4; ++f) o[f] = (f32x4){0.f, 0.f, 0.f, 0.f};
#pragma unroll
  for (int r = 0; r < 4; ++r) { m[r] = -INFINITY; l[r] = 0.f; }

  const float c = 0.18033688011112042f;  // log2(e) / sqrt(H)

  for (int tt = 0; tt < 32; ++tt) {
    asm volatile("" ::: "memory");  // keep LDS WAR ordering across iterations
    int tbase = tt * 64;

    // ---- S = Q K^T (raw, unscaled) ----
    f32x4 sf[4];
#pragma unroll
    for (int n = 0; n < 4; ++n) {
      const short* kr = Kb + boff + (size_t)(tbase + n * 16 + lq) * H_ + lg * 8;
      short8 kb0 = *reinterpret_cast<const short8*>(kr);
      short8 kb1 = *reinterpret_cast<const short8*>(kr + 32);
      sf[n] = (f32x4){0.f, 0.f, 0.f, 0.f};
      sf[n] = __builtin_amdgcn_mfma_f32_16x16x32_bf16(qa[0], kb0, sf[n], 0, 0, 0);
      sf[n] = __builtin_amdgcn_mfma_f32_16x16x32_bf16(qa[1], kb1, sf[n], 0, 0, 0);
    }

    // ---- online softmax (rows = lg*4+r, cols = n*16+lq) ----
    float mn[4], al[4], ts[4];
#pragma unroll
    for (int r = 0; r < 4; ++r) {
      float tm = fmaxf(fmaxf(sf[0][r], sf[1][r]), fmaxf(sf[2][r], sf[3][r]));
      tm = fmaxf(tm, __shfl_xor(tm, 1));
      tm = fmaxf(tm, __shfl_xor(tm, 2));
      tm = fmaxf(tm, __shfl_xor(tm, 4));
      tm = fmaxf(tm, __shfl_xor(tm, 8));
      mn[r] = fmaxf(m[r], tm);
      al[r] = exp2f((m[r] - mn[r]) * c);
      m[r] = mn[r];
      ts[r] = 0.f;
    }
#pragma unroll
    for (int n = 0; n < 4; ++n)
#pragma unroll
      for (int r = 0; r < 4; ++r) {
        float p = exp2f((sf[n][r] - mn[r]) * c);
        sf[n][r] = p;
        ts[r] += p;
      }
#pragma unroll
    for (int r = 0; r < 4; ++r) {
      ts[r] += __shfl_xor(ts[r], 1);
      ts[r] += __shfl_xor(ts[r], 2);
      ts[r] += __shfl_xor(ts[r], 4);
      ts[r] += __shfl_xor(ts[r], 8);
      l[r] = l[r] * al[r] + ts[r];
    }
#pragma unroll
    for (int f = 0; f < 4; ++f)
#pragma unroll
      for (int r = 0; r < 4; ++r) o[f][r] *= al[r];

    // ---- P -> bf16 via per-wave swizzled LDS (transpose to A-fragment) ----
#pragma unroll
    for (int n = 0; n < 4; ++n)
#pragma unroll
      for (int r = 0; r < 4; ++r) {
        int q = lg * 4 + r;
        *reinterpret_cast<short*>(pbase + swz(q, (n * 16 + lq) * 2)) = f2bf(sf[n][r]);
      }
    asm volatile("s_waitcnt lgkmcnt(0)" ::: "memory");
    short8 pa[2];
#pragma unroll
    for (int kk = 0; kk < 2; ++kk)
      pa[kk] = *reinterpret_cast<const short8*>(pbase + swz(lq, kk * 64 + lg * 16));

    // ---- O += P V  (B-frag contiguous thanks to Vt layout) ----
#pragma unroll
    for (int f = 0; f < 4; ++f) {
      const short* vr = Vt + ((size_t)b * H_ + f * 16 + lq) * S_ + tbase + lg * 8;
      short8 v0 = *reinterpret_cast<const short8*>(vr);
      short8 v1 = *reinterpret_cast<const short8*>(vr + 32);
      o[f] = __builtin_amdgcn_mfma_f32_16x16x32_bf16(pa[0], v0, o[f], 0, 0, 0);
      o[f] = __builtin_amdgcn_mfma_f32_16x16x32_bf16(pa[1], v1, o[f], 0, 0, 0);
    }
  }

  // ---- normalize + mean pool ----
  float inv[4];
#pragma unroll
  for (int r = 0; r < 4; ++r) inv[r] = 1.0f / l[r];
#pragma unroll
  for (int f = 0; f < 4; ++f) {
    float cs = o[f][0] * inv[0] + o[f][1] * inv[1] + o[f][2] * inv[2] + o[f][3] * inv[3];
    cs += __shfl_xor(cs, 16);
    cs += __shfl_xor(cs, 32);
    if (lane < 16) redbuf[w][f * 16 + lane] = cs;
  }
  __syncthreads();
  if (tid < 64) {
    float s = redbuf[0][tid] + redbuf[1][tid] + redbuf[2][tid] + redbuf[3][tid];
    atomicAdd(out + b * H_ + tid, s * (1.0f / (float)S_));
  }
}

// ---------------------------------------------------------------------------
extern "C" void kernel_launch(void* const* d_in, const int* in_sizes, int n_in,
                              void* d_out, int out_size, void* d_ws, size_t ws_size,
                              hipStream_t stream) {
  const float* in = (const float*)d_in[0];
  const float* Wq = (const float*)d_in[1];
  const float* bq = (const float*)d_in[2];
  const float* Wk = (const float*)d_in[3];
  const float* bk = (const float*)d_in[4];
  const float* Wv = (const float*)d_in[5];
  const float* bv = (const float*)d_in[6];
  float* out = (float*)d_out;

  char* ws = (char*)d_ws;
  short* Qb = (short*)(ws);                                   // 4 MiB
  short* Kb = (short*)(ws + (size_t)4 * 1024 * 1024);         // 4 MiB
  short* Vt = (short*)(ws + (size_t)8 * 1024 * 1024);         // 4 MiB
  short* Wt = (short*)(ws + (size_t)12 * 1024 * 1024);        // 192 KiB

  prep_weights<<<192, 256, 0, stream>>>(Wq, Wk, Wv, Wt);
  qkv_proj<<<512, 256, 0, stream>>>(in, Wt, bq, bk, bv, Qb, Kb, Vt);
  hipMemsetAsync(d_out, 0, (size_t)out_size * sizeof(float), stream);
  attn_kernel<<<512, 256, 0, stream>>>(Qb, Kb, Vt, out);
}

// Round 4
// 282.833 us; speedup vs baseline: 1.0181x; 1.0181x over previous
//
#include <hip/hip_runtime.h>
#include <hip/hip_bf16.h>

// Problem constants (AttentionLayer: B=16, S=2048, D=512, H=64)
#define B_ 16
#define S_ 2048
#define D_ 512
#define H_ 64

typedef __attribute__((ext_vector_type(8))) short short8;   // 8 x bf16 (4 VGPRs)
typedef __attribute__((ext_vector_type(4))) float f32x4;    // MFMA accumulator

static __device__ __forceinline__ short f2bf(float f) {
  union { __hip_bfloat16 h; short s; } u;
  u.h = __float2bfloat16(f);   // RNE
  return u.s;
}

// XOR-swizzle (16B granules within a 128B window keyed by row&7): breaks the
// 16-way bank conflict of stride-power-of-2 row-major LDS tiles (G4/T2).
static __device__ __forceinline__ int swz(int row, int byte_in_row) {
  int g = ((byte_in_row >> 4) ^ (row & 7)) & 7;
  return row * 128 + (g << 4) + (byte_in_row & 15);
}

// ---------------------------------------------------------------------------
// Kernel 0: transpose + convert weights to bf16; build combined bias[192].
// Wt[n][k]: n<64 -> Wq col n ; n<128 -> Wk ; else Wv.
// ---------------------------------------------------------------------------
__global__ void prep_weights(const float* __restrict__ Wq,
                             const float* __restrict__ Wk,
                             const float* __restrict__ Wv,
                             const float* __restrict__ bq,
                             const float* __restrict__ bk,
                             const float* __restrict__ bv,
                             short* __restrict__ Wt, float* __restrict__ biasAll) {
  int n = blockIdx.x;                       // 0..191
  const float* src  = (n < 64) ? Wq : (n < 128) ? Wk : Wv;
  const float* bsrc = (n < 64) ? bq : (n < 128) ? bk : bv;
  int col = n & 63;
  for (int k = threadIdx.x; k < D_; k += 256)
    Wt[n * D_ + k] = f2bf(src[k * H_ + col]);
  if (threadIdx.x == 0) biasAll[n] = bsrc[col];
}

// ---------------------------------------------------------------------------
// Kernel 1: fused QKV projection.  C[32768x192] = in[32768x512] * W[512x192].
// Grid 2048 blocks x 256 thr (4 waves); block owns 16 rows (contiguous 32 KB
// of input).  Input staged fp32->bf16 into XOR-swizzled LDS; wave w computes
// cols [w*48, w*48+48) (3 MFMA frags -> tiny VGPR -> full occupancy).
// Epilogue: bias, repack via LDS, coalesced Q/K stores, V stored TRANSPOSED
// (Vt[b][h][s]) directly.
// ---------------------------------------------------------------------------
__global__ __launch_bounds__(256) void qkv_proj(
    const float* __restrict__ in, const short* __restrict__ Wt,
    const float* __restrict__ biasAll,
    short* __restrict__ Qb, short* __restrict__ Kb, short* __restrict__ Vt) {
  int tid = threadIdx.x;
  int w = tid >> 6, lane = tid & 63, lq = lane & 15, lg = lane >> 4;
  int rowbase = blockIdx.x * 16;

  __shared__ short alds[8192];  // 16 KB: [16][512] bf16 swizzled; reused as ctile

  // ---- stage input tile (16x512 fp32 -> bf16, swizzled LDS) ----
  const float* src = in + (size_t)rowbase * D_;
#pragma unroll
  for (int c = 0; c < 4; ++c) {
    int e = c * 2048 + tid * 8;
    float4 a0 = *reinterpret_cast<const float4*>(src + e);
    float4 a1 = *reinterpret_cast<const float4*>(src + e + 4);
    short8 v;
    v[0] = f2bf(a0.x); v[1] = f2bf(a0.y); v[2] = f2bf(a0.z); v[3] = f2bf(a0.w);
    v[4] = f2bf(a1.x); v[5] = f2bf(a1.y); v[6] = f2bf(a1.z); v[7] = f2bf(a1.w);
    int row = e >> 9, colb = (e & 511) * 2;
    int addr = row * 1024 + (colb ^ ((row & 7) << 4));
    *reinterpret_cast<short8*>(reinterpret_cast<char*>(alds) + addr) = v;
  }
  __syncthreads();

  // ---- MFMA: 16 rows x 48 cols per wave, K-loop 16 x 32 ----
  f32x4 acc[3];
#pragma unroll
  for (int n = 0; n < 3; ++n) acc[n] = (f32x4){0.f, 0.f, 0.f, 0.f};
  int abase = lq * 1024;
  int axor = (lq & 7) << 4;
  const short* wbase = Wt + (w * 48 + lq) * D_ + lg * 8;
#pragma unroll 4
  for (int kk = 0; kk < 16; ++kk) {
    short8 af = *reinterpret_cast<const short8*>(
        reinterpret_cast<char*>(alds) + abase + ((kk * 64 + lg * 16) ^ axor));
#pragma unroll
    for (int n = 0; n < 3; ++n) {
      short8 bf = *reinterpret_cast<const short8*>(wbase + n * 16 * D_ + kk * 32);
      acc[n] = __builtin_amdgcn_mfma_f32_16x16x32_bf16(af, bf, acc[n], 0, 0, 0);
    }
  }
  __syncthreads();  // alds reads drained; safe to reuse as ctile

  // ---- epilogue: +bias, pack to ctile[16][208] bf16 ----
  short* ctile = alds;  // stride 208 elems = 416 B (16B-aligned rows)
#pragma unroll
  for (int n = 0; n < 3; ++n) {
    int col = w * 48 + n * 16 + lq;
    float bb = biasAll[col];
#pragma unroll
    for (int r = 0; r < 4; ++r)
      ctile[(lg * 4 + r) * 208 + col] = f2bf(acc[n][r] + bb);
  }
  __syncthreads();

  // ---- coalesced stores: Q (threads 0-127), K (threads 128-255) ----
  {
    int t2 = tid & 127;
    int row = t2 >> 3, cb = (t2 & 7) * 8;
    size_t g = (size_t)(rowbase + row) * H_ + cb;
    if (tid < 128)
      *reinterpret_cast<short8*>(Qb + g) =
          *reinterpret_cast<const short8*>(ctile + row * 208 + cb);
    else
      *reinterpret_cast<short8*>(Kb + g) =
          *reinterpret_cast<const short8*>(ctile + row * 208 + 64 + cb);
  }
  // ---- V transposed store: threads 0-63, one h-column (16 s-values = 32 B) ----
  if (tid < 64) {
    int h = tid;
    int b = rowbase >> 11, s0 = rowbase & (S_ - 1);
    short tmp[16];
#pragma unroll
    for (int r = 0; r < 16; ++r) tmp[r] = ctile[r * 208 + 128 + h];
    short8 v0, v1;
#pragma unroll
    for (int j = 0; j < 8; ++j) { v0[j] = tmp[j]; v1[j] = tmp[8 + j]; }
    short* dst = Vt + ((size_t)b * H_ + h) * S_ + s0;
    *reinterpret_cast<short8*>(dst) = v0;
    *reinterpret_cast<short8*>(dst + 8) = v1;
  }
}

// ---------------------------------------------------------------------------
// Kernel 2: flash attention + mean pool, KV split ACROSS WAVES.
// Grid = B * (S/16) = 2048 blocks x 4 waves (VGPR~64 -> 8 blocks/CU -> ~full
// occupancy).  All 4 waves share the block's 16 q-rows; wave w processes KV
// tiles [w*8, w*8+8).  Merge: each wave rebases its partial to m*=0
// (sc=e^{m/8} <= ~e^4, safe: raw scores ~N(0,8)), writes o*sc, l*sc to LDS
// (aliasing the dead P-transpose buffer), block sums across waves, then
// atomicAdd into out for the sequence mean-pool.  No global partials.
// ---------------------------------------------------------------------------
__global__ __launch_bounds__(256) void attn_pool(
    const short* __restrict__ Qb, const short* __restrict__ Kb,
    const short* __restrict__ Vt, float* __restrict__ out) {
  int tid = threadIdx.x;
  int w = tid >> 6, lane = tid & 63, lq = lane & 15, lg = lane >> 4;
  int qt = blockIdx.x & 127;
  int b = blockIdx.x >> 7;
  int boff = b * (S_ * H_);
  int qrow = qt * 16;

  // Loop phase uses [0, 8 KB) as 4 per-wave 2 KB P-buffers; merge phase
  // (after __syncthreads) reuses [0, 16.6 KB) as fp32 merge buffers.
  __shared__ __attribute__((aligned(16))) char smem[16704];
  char* pbase = smem + w * 2048;

  short8 qa[2];
#pragma unroll
  for (int kk = 0; kk < 2; ++kk)
    qa[kk] = *reinterpret_cast<const short8*>(
        Qb + boff + (qrow + lq) * H_ + kk * 32 + lg * 8);

  f32x4 o[4];
  float m[4], l[4];
#pragma unroll
  for (int f = 0; f < 4; ++f) o[f] = (f32x4){0.f, 0.f, 0.f, 0.f};
#pragma unroll
  for (int r = 0; r < 4; ++r) { m[r] = -INFINITY; l[r] = 0.f; }

  const float c = 0.18033688011112042f;  // log2(e) / sqrt(H)

  for (int tt = w * 8; tt < w * 8 + 8; ++tt) {
    asm volatile("" ::: "memory");  // keep LDS WAR ordering across iterations
    int tbase = tt * 64;

    // ---- S = Q K^T ----
    f32x4 sf[4];
#pragma unroll
    for (int n = 0; n < 4; ++n) {
      const short* kr = Kb + boff + (tbase + n * 16 + lq) * H_ + lg * 8;
      short8 kb0 = *reinterpret_cast<const short8*>(kr);
      short8 kb1 = *reinterpret_cast<const short8*>(kr + 32);
      sf[n] = (f32x4){0.f, 0.f, 0.f, 0.f};
      sf[n] = __builtin_amdgcn_mfma_f32_16x16x32_bf16(qa[0], kb0, sf[n], 0, 0, 0);
      sf[n] = __builtin_amdgcn_mfma_f32_16x16x32_bf16(qa[1], kb1, sf[n], 0, 0, 0);
    }

    // ---- online softmax (rows = lg*4+r, cols = n*16+lq) ----
    float mn[4], al[4], ts[4];
#pragma unroll
    for (int r = 0; r < 4; ++r) {
      float tm = fmaxf(fmaxf(sf[0][r], sf[1][r]), fmaxf(sf[2][r], sf[3][r]));
      tm = fmaxf(tm, __shfl_xor(tm, 1));
      tm = fmaxf(tm, __shfl_xor(tm, 2));
      tm = fmaxf(tm, __shfl_xor(tm, 4));
      tm = fmaxf(tm, __shfl_xor(tm, 8));
      mn[r] = fmaxf(m[r], tm);
      al[r] = exp2f((m[r] - mn[r]) * c);
      m[r] = mn[r];
      ts[r] = 0.f;
    }
#pragma unroll
    for (int n = 0; n < 4; ++n)
#pragma unroll
      for (int r = 0; r < 4; ++r) {
        float p = exp2f((sf[n][r] - mn[r]) * c);
        sf[n][r] = p;
        ts[r] += p;
      }
#pragma unroll
    for (int r = 0; r < 4; ++r) {
      ts[r] += __shfl_xor(ts[r], 1);
      ts[r] += __shfl_xor(ts[r], 2);
      ts[r] += __shfl_xor(ts[r], 4);
      ts[r] += __shfl_xor(ts[r], 8);
      l[r] = l[r] * al[r] + ts[r];
    }
#pragma unroll
    for (int f = 0; f < 4; ++f)
#pragma unroll
      for (int r = 0; r < 4; ++r) o[f][r] *= al[r];

    // ---- P -> bf16 via per-wave swizzled LDS (transpose to A-fragment) ----
#pragma unroll
    for (int n = 0; n < 4; ++n)
#pragma unroll
      for (int r = 0; r < 4; ++r) {
        int q = lg * 4 + r;
        *reinterpret_cast<short*>(pbase + swz(q, (n * 16 + lq) * 2)) = f2bf(sf[n][r]);
      }
    asm volatile("s_waitcnt lgkmcnt(0)" ::: "memory");
    short8 pa[2];
#pragma unroll
    for (int kk = 0; kk < 2; ++kk)
      pa[kk] = *reinterpret_cast<const short8*>(pbase + swz(lq, kk * 64 + lg * 16));

    // ---- O += P V  (B-frag contiguous thanks to Vt layout) ----
#pragma unroll
    for (int f = 0; f < 4; ++f) {
      const short* vr = Vt + ((size_t)b * H_ + f * 16 + lq) * S_ + tbase + lg * 8;
      short8 v0 = *reinterpret_cast<const short8*>(vr);
      short8 v1 = *reinterpret_cast<const short8*>(vr + 32);
      o[f] = __builtin_amdgcn_mfma_f32_16x16x32_bf16(pa[0], v0, o[f], 0, 0, 0);
      o[f] = __builtin_amdgcn_mfma_f32_16x16x32_bf16(pa[1], v1, o[f], 0, 0, 0);
    }
  }

  // ---- cross-wave merge in LDS (rebase to m*=0) + mean pool ----
  float sc[4];
#pragma unroll
  for (int r = 0; r < 4; ++r) sc[r] = exp2f(m[r] * c);

  __syncthreads();  // all waves done with P-buffers; smem reusable
  float* mo = (float*)smem;            // [4][16][64] = 16384 B
  float* ml = (float*)(smem + 16384);  // [4][16]     = 256 B
#pragma unroll
  for (int f = 0; f < 4; ++f)
#pragma unroll
    for (int r = 0; r < 4; ++r)
      mo[(w * 16 + lg * 4 + r) * 64 + f * 16 + lq] = o[f][r] * sc[r];
  if (lq == 0) {
#pragma unroll
    for (int r = 0; r < 4; ++r) ml[w * 16 + lg * 4 + r] = l[r] * sc[r];
  }
  __syncthreads();

  int col = tid & 63, rowb = tid >> 6;
  float acc = 0.f;
#pragma unroll
  for (int rr = 0; rr < 4; ++rr) {
    int row = rowb * 4 + rr;
    float lt = ml[row] + ml[16 + row] + ml[32 + row] + ml[48 + row];
    float ot = mo[row * 64 + col] + mo[(16 + row) * 64 + col] +
               mo[(32 + row) * 64 + col] + mo[(48 + row) * 64 + col];
    acc += ot / lt;
  }
  atomicAdd(out + b * H_ + col, acc * (1.0f / (float)S_));
}

// ---------------------------------------------------------------------------
extern "C" void kernel_launch(void* const* d_in, const int* in_sizes, int n_in,
                              void* d_out, int out_size, void* d_ws, size_t ws_size,
                              hipStream_t stream) {
  const float* in = (const float*)d_in[0];
  const float* Wq = (const float*)d_in[1];
  const float* bq = (const float*)d_in[2];
  const float* Wk = (const float*)d_in[3];
  const float* bk = (const float*)d_in[4];
  const float* Wv = (const float*)d_in[5];
  const float* bv = (const float*)d_in[6];
  float* out = (float*)d_out;

  char* ws = (char*)d_ws;
  short* Qb      = (short*)(ws);                                   // 4 MiB
  short* Kb      = (short*)(ws + (size_t)4 * 1024 * 1024);         // 4 MiB
  short* Vt      = (short*)(ws + (size_t)8 * 1024 * 1024);         // 4 MiB
  short* Wt      = (short*)(ws + (size_t)12 * 1024 * 1024);        // 192 KiB
  float* biasAll = (float*)(ws + (size_t)12 * 1024 * 1024 + 192 * 1024);  // 768 B
  // total workspace footprint: ~12.2 MiB (validated in round 1)

  prep_weights<<<192, 256, 0, stream>>>(Wq, Wk, Wv, bq, bk, bv, Wt, biasAll);
  qkv_proj<<<2048, 256, 0, stream>>>(in, Wt, biasAll, Qb, Kb, Vt);
  hipMemsetAsync(d_out, 0, (size_t)out_size * sizeof(float), stream);
  attn_pool<<<2048, 256, 0, stream>>>(Qb, Kb, Vt, out);
}

// Round 5
// 210.567 us; speedup vs baseline: 1.3675x; 1.3432x over previous
//
#include <hip/hip_runtime.h>
#include <hip/hip_bf16.h>

// Problem constants (AttentionLayer: B=16, S=2048, D=512, H=64)
#define B_ 16
#define S_ 2048
#define D_ 512
#define H_ 64

typedef __attribute__((ext_vector_type(8))) short short8;    // 8 x bf16 (4 VGPRs)
typedef __attribute__((ext_vector_type(4))) float f32x4;
typedef __attribute__((ext_vector_type(16))) float f32x16;   // 32x32 MFMA accumulator

static __device__ __forceinline__ short f2bf(float f) {
  union { __hip_bfloat16 h; short s; } u;
  u.h = __float2bfloat16(f);   // RNE
  return u.s;
}

// pack two fp32 -> one u32 of 2 bf16 (RNE).  src0 -> low 16 bits.
static __device__ __forceinline__ unsigned cvtpk(float lo, float hi) {
  unsigned r;
  asm("v_cvt_pk_bf16_f32 %0, %1, %2" : "=v"(r) : "v"(lo), "v"(hi));
  return r;
}

// ---------------------------------------------------------------------------
// Kernel 0: transpose + convert weights to bf16; combined bias[192].
// Wt[n][k]: n<64 -> Wq col n ; n<128 -> Wk ; else Wv.
// ---------------------------------------------------------------------------
__global__ void prep_weights(const float* __restrict__ Wq,
                             const float* __restrict__ Wk,
                             const float* __restrict__ Wv,
                             const float* __restrict__ bq,
                             const float* __restrict__ bk,
                             const float* __restrict__ bv,
                             short* __restrict__ Wt, float* __restrict__ biasAll) {
  int n = blockIdx.x;                       // 0..191
  const float* src  = (n < 64) ? Wq : (n < 128) ? Wk : Wv;
  const float* bsrc = (n < 64) ? bq : (n < 128) ? bk : bv;
  int col = n & 63;
  for (int k = threadIdx.x; k < D_; k += 256)
    Wt[n * D_ + k] = f2bf(src[k * H_ + col]);
  if (threadIdx.x == 0) biasAll[n] = bsrc[col];
}

// ---------------------------------------------------------------------------
// Kernel 1: fused QKV projection on 32x32x16 MFMA, no LDS, no barriers.
// Grid 512 blocks x 384 thr (6 waves).  Block owns 64 input rows.  Wave
// (rh = w&1, ct = w>>1): rows [rh*32,+32), output cols [ct*64,+64) where
// ct=0 -> Q, 1 -> K, 2 -> V.  A-frag: lane reads in[row=rowbase+rh*32+(l&31)]
// [k=(l>>5)*8+j] fp32->bf16 in-register (cvt_pk).  B-frag: Wt[col][k] 16B.
// Epilogue: +bias, scalar 2B stores (consecutive lanes = consecutive cols ->
// coalesced); V stored transposed Vt[b][h][s] (wave dirties full 64B lines
// across its 16 regs).
// ---------------------------------------------------------------------------
__global__ __launch_bounds__(384) void qkv_proj(
    const float* __restrict__ in, const short* __restrict__ Wt,
    const float* __restrict__ biasAll,
    short* __restrict__ Qb, short* __restrict__ Kb, short* __restrict__ Vt) {
  int tid = threadIdx.x;
  int w = tid >> 6, l = tid & 63, cl = l & 31, h = l >> 5;
  int rh = w & 1, ct = w >> 1;           // row-half, col-tile(Q/K/V)
  int rowbase = blockIdx.x * 64;

  const float* ap = in + (size_t)(rowbase + rh * 32 + cl) * D_;
  const short* wb0 = Wt + (ct * 64 + cl) * D_ + h * 8;
  const short* wb1 = wb0 + 32 * D_;
  float bias0 = biasAll[ct * 64 + cl];
  float bias1 = biasAll[ct * 64 + 32 + cl];

  f32x16 a0, a1;
#pragma unroll
  for (int i = 0; i < 16; ++i) { a0[i] = 0.f; a1[i] = 0.f; }

#pragma unroll 4
  for (int ks = 0; ks < 32; ++ks) {
    int off = ks * 16 + h * 8;
    float4 f0 = *reinterpret_cast<const float4*>(ap + off);
    float4 f1 = *reinterpret_cast<const float4*>(ap + off + 4);
    union { unsigned u[4]; short8 v; } af;
    af.u[0] = cvtpk(f0.x, f0.y);
    af.u[1] = cvtpk(f0.z, f0.w);
    af.u[2] = cvtpk(f1.x, f1.y);
    af.u[3] = cvtpk(f1.z, f1.w);
    short8 b0 = *reinterpret_cast<const short8*>(wb0 + ks * 16);
    short8 b1 = *reinterpret_cast<const short8*>(wb1 + ks * 16);
    a0 = __builtin_amdgcn_mfma_f32_32x32x16_bf16(af.v, b0, a0, 0, 0, 0);
    a1 = __builtin_amdgcn_mfma_f32_32x32x16_bf16(af.v, b1, a1, 0, 0, 0);
  }

  // C/D: col = l&31 (our out-col), row = (reg&3)+8*(reg>>2)+4*(l>>5)  [m74/m101]
  int b = rowbase >> 11, srow0 = rowbase & (S_ - 1);
#pragma unroll
  for (int i = 0; i < 16; ++i) {
    int rl = (i & 3) + 8 * (i >> 2) + 4 * h + rh * 32;   // 0..63 within block
    size_t grow = (size_t)(rowbase + rl);
    short v0 = f2bf(a0[i] + bias0);
    short v1 = f2bf(a1[i] + bias1);
    if (ct == 0) {
      Qb[grow * H_ + cl] = v0;
      Qb[grow * H_ + 32 + cl] = v1;
    } else if (ct == 1) {
      Kb[grow * H_ + cl] = v0;
      Kb[grow * H_ + 32 + cl] = v1;
    } else {
      Vt[((size_t)b * H_ + cl) * S_ + srow0 + rl] = v0;
      Vt[((size_t)b * H_ + 32 + cl) * S_ + srow0 + rl] = v1;
    }
  }
}

// ---------------------------------------------------------------------------
// Kernel 2: flash attention + mean pool, swapped 32x32 QK^T, lane-local
// softmax, P in registers (cvt_pk + 2 shfl per k-slice), zero LDS in loop.
// Grid = B * (S/32 q-chunks) = 1024 blocks x 4 waves; all waves share the
// block's 32 q-rows; wave w sweeps keys [w*512,+512) in 16 tiles of 32.
// Merge: rebase to m*=0 (validated r4), in-LDS cross-wave sum + mean pool.
// ---------------------------------------------------------------------------
__global__ __launch_bounds__(256, 4) void attn_pool(
    const short* __restrict__ Qb, const short* __restrict__ Kb,
    const short* __restrict__ Vt, float* __restrict__ out) {
  int tid = threadIdx.x;
  int w = tid >> 6, l = tid & 63, q = l & 31, h = l >> 5;
  int qc = blockIdx.x & 63, b = blockIdx.x >> 6;
  size_t boff = (size_t)b * (S_ * H_);
  int qrow = qc * 32;

  const float c = 0.18033688011112042f;  // log2(e) / sqrt(H)

  // Q fragments: B-operand, lane holds col=q, d=(l>>5)*8+j per 16-d slice.
  short8 qa[4];
#pragma unroll
  for (int s4 = 0; s4 < 4; ++s4)
    qa[s4] = *reinterpret_cast<const short8*>(
        Qb + boff + (size_t)(qrow + q) * H_ + s4 * 16 + h * 8);

  f32x16 o0, o1;
#pragma unroll
  for (int i = 0; i < 16; ++i) { o0[i] = 0.f; o1[i] = 0.f; }
  float m = -INFINITY, lsum = 0.f;

  const short* vbase = Vt + ((size_t)b * H_ + q) * S_;

  for (int it = 0; it < 16; ++it) {
    int tbase = w * 512 + it * 32;

    // ---- S^T[key][q] = K·Q^T : A-frag = K rows (key=l&31), B-frag = qa ----
    const short* kp = Kb + boff + (size_t)(tbase + q) * H_ + h * 8;
    f32x16 st;
#pragma unroll
    for (int i = 0; i < 16; ++i) st[i] = 0.f;
#pragma unroll
    for (int s4 = 0; s4 < 4; ++s4) {
      short8 ka = *reinterpret_cast<const short8*>(kp + s4 * 16);
      st = __builtin_amdgcn_mfma_f32_32x32x16_bf16(ka, qa[s4], st, 0, 0, 0);
    }
    // lane (q, h) holds keys k = (reg&3) + 8*(reg>>2) + 4h  (16 of 32)

    // ---- lane-local online softmax (row q entirely in this lane + partner) --
    float tm = st[0];
#pragma unroll
    for (int i = 1; i < 16; ++i) tm = fmaxf(tm, st[i]);
    tm = fmaxf(tm, __shfl_xor(tm, 32));
    float mn = fmaxf(m, tm);
    float cmn = mn * c;
    float al = exp2f(m * c - cmn);       // 0 on first tile (m = -inf)
    float p[16];
    float ts = 0.f;
#pragma unroll
    for (int i = 0; i < 16; ++i) {
      p[i] = exp2f(st[i] * c - cmn);
      ts += p[i];
    }
    ts += __shfl_xor(ts, 32);
    lsum = lsum * al + ts;
    m = mn;
#pragma unroll
    for (int i = 0; i < 16; ++i) { o0[i] *= al; o1[i] *= al; }

    // ---- P -> bf16 B-fragments, in-register (T12) ----
    // quads: regs 4t..4t+3 hold k = 8t + 4h + {0..3}; pack to words W[t][0..1]
    unsigned W[4][2];
#pragma unroll
    for (int t = 0; t < 4; ++t) {
      W[t][0] = cvtpk(p[4 * t + 0], p[4 * t + 1]);
      W[t][1] = cvtpk(p[4 * t + 2], p[4 * t + 3]);
    }
    // B-frag slice s needs k = 16s+8h+{0..7}: words[0..1] from half-0's quad
    // t=2s+h, words[2..3] from half-1's quad t=2s+h  -> keep own W[2s+h],
    // send W[2s+(1-h)] to partner via shfl_xor(32).
    short8 bf[2];
#pragma unroll
    for (int s = 0; s < 2; ++s) {
      unsigned k0 = h ? W[2 * s + 1][0] : W[2 * s][0];
      unsigned k1 = h ? W[2 * s + 1][1] : W[2 * s][1];
      unsigned s0 = h ? W[2 * s][0] : W[2 * s + 1][0];
      unsigned s1 = h ? W[2 * s][1] : W[2 * s + 1][1];
      unsigned r0 = (unsigned)__shfl_xor((int)s0, 32);
      unsigned r1 = (unsigned)__shfl_xor((int)s1, 32);
      union { unsigned u[4]; short8 v; } bb;
      bb.u[0] = h ? r0 : k0;
      bb.u[1] = h ? r1 : k1;
      bb.u[2] = h ? k0 : r0;
      bb.u[3] = h ? k1 : r1;
      bf[s] = bb.v;
    }

    // ---- O^T[dv][q] += V^T · P : A-frag = Vt rows (dv), B-frag = bf ----
    const short* vp = vbase + tbase + h * 8;
#pragma unroll
    for (int s = 0; s < 2; ++s) {
      short8 va0 = *reinterpret_cast<const short8*>(vp + s * 16);
      short8 va1 = *reinterpret_cast<const short8*>(vp + 32 * S_ + s * 16);
      o0 = __builtin_amdgcn_mfma_f32_32x32x16_bf16(va0, bf[s], o0, 0, 0, 0);
      o1 = __builtin_amdgcn_mfma_f32_32x32x16_bf16(va1, bf[s], o1, 0, 0, 0);
    }
  }

  // ---- cross-wave merge (rebase to m*=0) + mean pool ----
  float sc = exp2f(m * c);

  __shared__ float mo[4][64][33];   // [wave][dv][q], +1 pad (reduce reads)
  __shared__ float mls[4][32];
  __shared__ float red[4][64];
#pragma unroll
  for (int i = 0; i < 16; ++i) {
    int dv = (i & 3) + 8 * (i >> 2) + 4 * h;
    mo[w][dv][q] = o0[i] * sc;
    mo[w][32 + dv][q] = o1[i] * sc;
  }
  if (h == 0) mls[w][q] = lsum * sc;
  __syncthreads();

  int dv = tid & 63, qg = tid >> 6;
  float acc = 0.f;
#pragma unroll
  for (int j = 0; j < 8; ++j) {
    int qq = qg * 8 + j;
    float L = mls[0][qq] + mls[1][qq] + mls[2][qq] + mls[3][qq];
    float num = mo[0][dv][qq] + mo[1][dv][qq] + mo[2][dv][qq] + mo[3][dv][qq];
    acc += num / L;
  }
  red[qg][dv] = acc;
  __syncthreads();
  if (tid < 64) {
    float s = red[0][tid] + red[1][tid] + red[2][tid] + red[3][tid];
    atomicAdd(out + b * H_ + tid, s * (1.0f / (float)S_));
  }
}

// ---------------------------------------------------------------------------
extern "C" void kernel_launch(void* const* d_in, const int* in_sizes, int n_in,
                              void* d_out, int out_size, void* d_ws, size_t ws_size,
                              hipStream_t stream) {
  const float* in = (const float*)d_in[0];
  const float* Wq = (const float*)d_in[1];
  const float* bq = (const float*)d_in[2];
  const float* Wk = (const float*)d_in[3];
  const float* bk = (const float*)d_in[4];
  const float* Wv = (const float*)d_in[5];
  const float* bv = (const float*)d_in[6];
  float* out = (float*)d_out;

  char* ws = (char*)d_ws;
  short* Qb      = (short*)(ws);                                   // 4 MiB
  short* Kb      = (short*)(ws + (size_t)4 * 1024 * 1024);         // 4 MiB
  short* Vt      = (short*)(ws + (size_t)8 * 1024 * 1024);         // 4 MiB
  short* Wt      = (short*)(ws + (size_t)12 * 1024 * 1024);        // 192 KiB
  float* biasAll = (float*)(ws + (size_t)12 * 1024 * 1024 + 192 * 1024);  // 768 B
  // total workspace footprint: ~12.2 MiB (validated in rounds 1 and 4)

  prep_weights<<<192, 256, 0, stream>>>(Wq, Wk, Wv, bq, bk, bv, Wt, biasAll);
  qkv_proj<<<512, 384, 0, stream>>>(in, Wt, biasAll, Qb, Kb, Vt);
  hipMemsetAsync(d_out, 0, (size_t)out_size * sizeof(float), stream);
  attn_pool<<<1024, 256, 0, stream>>>(Qb, Kb, Vt, out);
}

// Round 6
// 189.506 us; speedup vs baseline: 1.5195x; 1.1111x over previous
//
#include <hip/hip_runtime.h>
#include <hip/hip_bf16.h>

// Problem constants (AttentionLayer: B=16, S=2048, D=512, H=64)
#define B_ 16
#define S_ 2048
#define D_ 512
#define H_ 64

typedef __attribute__((ext_vector_type(8))) short short8;    // 8 x bf16 (4 VGPRs)
typedef __attribute__((ext_vector_type(16))) float f32x16;   // 32x32 MFMA accumulator

static __device__ __forceinline__ short f2bf(float f) {
  union { __hip_bfloat16 h; short s; } u;
  u.h = __float2bfloat16(f);   // RNE
  return u.s;
}
static __device__ __forceinline__ float b2f(short s) {
  union { float f; unsigned u; } x;
  x.u = ((unsigned)(unsigned short)s) << 16;
  return x.f;
}
// pack two fp32 -> one u32 of 2 bf16 (RNE).  src0 -> low 16 bits.
static __device__ __forceinline__ unsigned cvtpk(float lo, float hi) {
  unsigned r;
  asm("v_cvt_pk_bf16_f32 %0, %1, %2" : "=v"(r) : "v"(lo), "v"(hi));
  return r;
}

// ---------------------------------------------------------------------------
// Kernel 0: transpose + convert weights to bf16; combined bias[192].
// Wt[n][k]: n<64 -> Wq col n (PRE-SCALED by log2e/sqrt(H)) ; n<128 -> Wk ;
// else Wv.  Scaling Q at the source puts QK^T scores directly in the exp2
// domain -> attention needs no per-score multiply.
// ---------------------------------------------------------------------------
__global__ void prep_weights(const float* __restrict__ Wq,
                             const float* __restrict__ Wk,
                             const float* __restrict__ Wv,
                             const float* __restrict__ bq,
                             const float* __restrict__ bk,
                             const float* __restrict__ bv,
                             short* __restrict__ Wt, float* __restrict__ biasAll) {
  int n = blockIdx.x;                       // 0..191
  const float* src  = (n < 64) ? Wq : (n < 128) ? Wk : Wv;
  const float* bsrc = (n < 64) ? bq : (n < 128) ? bk : bv;
  float scale = (n < 64) ? 0.18033688011112042f : 1.0f;  // log2(e)/sqrt(64)
  int col = n & 63;
  for (int k = threadIdx.x; k < D_; k += 256)
    Wt[n * D_ + k] = f2bf(src[k * H_ + col] * scale);
  if (threadIdx.x == 0) biasAll[n] = bsrc[col] * scale;
}

// ---------------------------------------------------------------------------
// Kernel 1: fused QKV projection, LDS-staged.  Grid 1024 x 384 (6 waves).
// Block owns 32 input rows; input tile (32x512 fp32) staged ONCE to
// XOR-swizzled bf16 LDS (kills the 3x redundant global reads + converts of
// the previous version).  Wave ct computes out-cols [ct*32,+32) (Q:0-1,
// K:2-3, V:4-5) via 32x 32x32x16 MFMA.  V transposed through a small LDS
// tile -> coalesced 16B stores (was: fully scattered 2B stores).
// ---------------------------------------------------------------------------
__global__ __launch_bounds__(384) void qkv_proj(
    const float* __restrict__ in, const short* __restrict__ Wt,
    const float* __restrict__ biasAll,
    short* __restrict__ Qb, short* __restrict__ Kb, short* __restrict__ Vt) {
  int tid = threadIdx.x;
  int w = tid >> 6, l = tid & 63, cl = l & 31, h = l >> 5;
  int rowbase = blockIdx.x * 32;

  __shared__ short alds[16384];     // 32 KB: 32 rows x 1024 B, XOR-swizzled
  __shared__ short vtile[64][40];   // 5 KB transpose staging (80B rows, 16B-aligned)

  // ---- stage 32x512 fp32 -> bf16 swizzled LDS (tid<256: 8 tasks x 8 elems) --
  if (tid < 256) {
#pragma unroll
    for (int itr = 0; itr < 8; ++itr) {
      int i = itr * 256 + tid;              // 0..2047
      int r = i >> 6, c8 = i & 63;
      const float* sp = in + (size_t)(rowbase + r) * D_ + c8 * 8;
      float4 f0 = *reinterpret_cast<const float4*>(sp);
      float4 f1 = *reinterpret_cast<const float4*>(sp + 4);
      union { unsigned u[4]; short8 v; } pk;
      pk.u[0] = cvtpk(f0.x, f0.y); pk.u[1] = cvtpk(f0.z, f0.w);
      pk.u[2] = cvtpk(f1.x, f1.y); pk.u[3] = cvtpk(f1.z, f1.w);
      int addr = r * 1024 + ((c8 * 16) ^ ((r & 7) << 4));
      *reinterpret_cast<short8*>(reinterpret_cast<char*>(alds) + addr) = pk.v;
    }
  }
  __syncthreads();

  // ---- MFMA: A = input rows (lane cl), B = Wt row (out-col) w*32+cl ----
  const short* wb = Wt + (w * 32 + cl) * D_ + h * 8;
  f32x16 acc;
#pragma unroll
  for (int i = 0; i < 16; ++i) acc[i] = 0.f;
  int abase = cl * 1024, axor = (cl & 7) << 4;
#pragma unroll 8
  for (int ks = 0; ks < 32; ++ks) {
    short8 af = *reinterpret_cast<const short8*>(
        reinterpret_cast<char*>(alds) + abase + ((ks * 32 + h * 16) ^ axor));
    short8 bf = *reinterpret_cast<const short8*>(wb + ks * 16);
    acc = __builtin_amdgcn_mfma_f32_32x32x16_bf16(af, bf, acc, 0, 0, 0);
  }

  float bias = biasAll[w * 32 + cl];
  // C/D: out-col = cl, input-row rl = (i&3)+8*(i>>2)+4*h   [validated r5]
  if (w < 4) {
    short* dst = (w < 2) ? Qb : Kb;
    int cb = (w & 1) * 32 + cl;
#pragma unroll
    for (int i = 0; i < 16; ++i) {
      int rl = (i & 3) + 8 * (i >> 2) + 4 * h;
      dst[(size_t)(rowbase + rl) * H_ + cb] = f2bf(acc[i] + bias);
    }
  } else {
#pragma unroll
    for (int i = 0; i < 16; ++i) {
      int rl = (i & 3) + 8 * (i >> 2) + 4 * h;
      vtile[(w - 4) * 32 + cl][rl] = f2bf(acc[i] + bias);
    }
  }
  __syncthreads();
  // ---- coalesced transposed V store: 256 tasks = 64 h x 4 chunks of 8 ----
  if (tid < 256) {
    int hh = tid >> 2, ch = tid & 3;
    short8 v = *reinterpret_cast<const short8*>(&vtile[hh][ch * 8]);
    int b = rowbase >> 11, s0 = rowbase & (S_ - 1);
    *reinterpret_cast<short8*>(Vt + ((size_t)b * H_ + hh) * S_ + s0 + ch * 8) = v;
  }
}

// ---------------------------------------------------------------------------
// Kernel 2: flash attention + mean pool.  Swapped 32x32 QK^T, lane-local
// softmax in the exp2 domain (scale folded into Q), defer-max rescale (T13),
// K(it+1)/V(it) loads issued BEFORE the QK MFMA so L2 latency hides under
// compute, setprio around MFMA clusters (T5), P in registers (cvt_pk +
// shfl_xor(32)), bf16 cross-wave merge in LDS.
// Grid = B * (S/32) = 1024 blocks x 4 waves; wave w sweeps keys [w*512,+512).
// ---------------------------------------------------------------------------
__global__ __launch_bounds__(256) void attn_pool(
    const short* __restrict__ Qb, const short* __restrict__ Kb,
    const short* __restrict__ Vt, float* __restrict__ out) {
  int tid = threadIdx.x;
  int w = tid >> 6, l = tid & 63, q = l & 31, h = l >> 5;
  int qc = blockIdx.x & 63, b = blockIdx.x >> 6;
  size_t boff = (size_t)b * (S_ * H_);
  int qrow = qc * 32;

  // Q fragments (pre-scaled by log2e/sqrt(H) at projection time)
  short8 qa[4];
#pragma unroll
  for (int s4 = 0; s4 < 4; ++s4)
    qa[s4] = *reinterpret_cast<const short8*>(
        Qb + boff + (size_t)(qrow + q) * H_ + s4 * 16 + h * 8);

  f32x16 o0, o1;
#pragma unroll
  for (int i = 0; i < 16; ++i) { o0[i] = 0.f; o1[i] = 0.f; }
  float m = -INFINITY, lsum = 0.f;

  const short* vrow = Vt + ((size_t)b * H_ + q) * S_;

  // preload K tile 0
  short8 ka[4];
  {
    const short* kp = Kb + boff + (size_t)(w * 512 + q) * H_ + h * 8;
#pragma unroll
    for (int s4 = 0; s4 < 4; ++s4)
      ka[s4] = *reinterpret_cast<const short8*>(kp + s4 * 16);
  }

#pragma unroll
  for (int it = 0; it < 16; ++it) {
    int tbase = w * 512 + it * 32;

    // ---- issue V(it) + prefetch K(it+1) before any MFMA ----
    const short* vp = vrow + tbase + h * 8;
    short8 va0 = *reinterpret_cast<const short8*>(vp);
    short8 va1 = *reinterpret_cast<const short8*>(vp + 16);
    short8 va2 = *reinterpret_cast<const short8*>(vp + 32 * S_);
    short8 va3 = *reinterpret_cast<const short8*>(vp + 32 * S_ + 16);
    short8 kn[4];
    if (it < 15) {
      const short* kp = Kb + boff + (size_t)(tbase + 32 + q) * H_ + h * 8;
#pragma unroll
      for (int s4 = 0; s4 < 4; ++s4)
        kn[s4] = *reinterpret_cast<const short8*>(kp + s4 * 16);
    }

    // ---- S^T[key][q] = K·Q^T (already in log2 domain) ----
    f32x16 st;
#pragma unroll
    for (int i = 0; i < 16; ++i) st[i] = 0.f;
    __builtin_amdgcn_s_setprio(1);
#pragma unroll
    for (int s4 = 0; s4 < 4; ++s4)
      st = __builtin_amdgcn_mfma_f32_32x32x16_bf16(ka[s4], qa[s4], st, 0, 0, 0);
    __builtin_amdgcn_s_setprio(0);

    // ---- lane-local online softmax with defer-max (T13, THR=8) ----
    float tm = st[0];
#pragma unroll
    for (int i = 1; i < 16; ++i) tm = fmaxf(tm, st[i]);
    tm = fmaxf(tm, __shfl_xor(tm, 32));
    if (__any(tm > m + 8.0f)) {
      float mn = fmaxf(m, tm);
      float al = exp2f(m - mn);
      lsum *= al;
#pragma unroll
      for (int i = 0; i < 16; ++i) { o0[i] *= al; o1[i] *= al; }
      m = mn;
    }
    float ts = 0.f;
    unsigned W[4][2];
#pragma unroll
    for (int t = 0; t < 4; ++t) {
      float p0 = exp2f(st[4 * t + 0] - m);
      float p1 = exp2f(st[4 * t + 1] - m);
      float p2 = exp2f(st[4 * t + 2] - m);
      float p3 = exp2f(st[4 * t + 3] - m);
      ts += (p0 + p1) + (p2 + p3);
      W[t][0] = cvtpk(p0, p1);
      W[t][1] = cvtpk(p2, p3);
    }
    ts += __shfl_xor(ts, 32);
    lsum += ts;

    // ---- P -> bf16 B-fragments in-register (T12) ----
    short8 bf[2];
#pragma unroll
    for (int s = 0; s < 2; ++s) {
      unsigned k0 = h ? W[2 * s + 1][0] : W[2 * s][0];
      unsigned k1 = h ? W[2 * s + 1][1] : W[2 * s][1];
      unsigned s0 = h ? W[2 * s][0] : W[2 * s + 1][0];
      unsigned s1 = h ? W[2 * s][1] : W[2 * s + 1][1];
      unsigned r0 = (unsigned)__shfl_xor((int)s0, 32);
      unsigned r1 = (unsigned)__shfl_xor((int)s1, 32);
      union { unsigned u[4]; short8 v; } bb;
      bb.u[0] = h ? r0 : k0;
      bb.u[1] = h ? r1 : k1;
      bb.u[2] = h ? k0 : r0;
      bb.u[3] = h ? k1 : r1;
      bf[s] = bb.v;
    }

    // ---- O^T[dv][q] += V^T · P ----
    __builtin_amdgcn_s_setprio(1);
    o0 = __builtin_amdgcn_mfma_f32_32x32x16_bf16(va0, bf[0], o0, 0, 0, 0);
    o0 = __builtin_amdgcn_mfma_f32_32x32x16_bf16(va1, bf[1], o0, 0, 0, 0);
    o1 = __builtin_amdgcn_mfma_f32_32x32x16_bf16(va2, bf[0], o1, 0, 0, 0);
    o1 = __builtin_amdgcn_mfma_f32_32x32x16_bf16(va3, bf[1], o1, 0, 0, 0);
    __builtin_amdgcn_s_setprio(0);

    if (it < 15) {
#pragma unroll
      for (int s4 = 0; s4 < 4; ++s4) ka[s4] = kn[s4];
    }
  }

  // ---- cross-wave merge (rebase to m*=0, bf16 staging) + mean pool ----
  float sc = exp2f(m);

  __shared__ short mo[4][64][34];   // 17408 B (bf16; +2 pad)
  __shared__ float mls[4][32];      // 512 B
  __shared__ float red[4][64];      // 1024 B
#pragma unroll
  for (int i = 0; i < 16; ++i) {
    int dv = (i & 3) + 8 * (i >> 2) + 4 * h;
    mo[w][dv][q] = f2bf(o0[i] * sc);
    mo[w][32 + dv][q] = f2bf(o1[i] * sc);
  }
  if (h == 0) mls[w][q] = lsum * sc;
  __syncthreads();

  int dv = tid & 63, qg = tid >> 6;
  float acc = 0.f;
#pragma unroll
  for (int j = 0; j < 8; ++j) {
    int qq = qg * 8 + j;
    float L = mls[0][qq] + mls[1][qq] + mls[2][qq] + mls[3][qq];
    float num = b2f(mo[0][dv][qq]) + b2f(mo[1][dv][qq]) +
                b2f(mo[2][dv][qq]) + b2f(mo[3][dv][qq]);
    acc += num / L;
  }
  red[qg][dv] = acc;
  __syncthreads();
  if (tid < 64) {
    float s = red[0][tid] + red[1][tid] + red[2][tid] + red[3][tid];
    atomicAdd(out + b * H_ + tid, s * (1.0f / (float)S_));
  }
}

// ---------------------------------------------------------------------------
extern "C" void kernel_launch(void* const* d_in, const int* in_sizes, int n_in,
                              void* d_out, int out_size, void* d_ws, size_t ws_size,
                              hipStream_t stream) {
  const float* in = (const float*)d_in[0];
  const float* Wq = (const float*)d_in[1];
  const float* bq = (const float*)d_in[2];
  const float* Wk = (const float*)d_in[3];
  const float* bk = (const float*)d_in[4];
  const float* Wv = (const float*)d_in[5];
  const float* bv = (const float*)d_in[6];
  float* out = (float*)d_out;

  char* ws = (char*)d_ws;
  short* Qb      = (short*)(ws);                                   // 4 MiB
  short* Kb      = (short*)(ws + (size_t)4 * 1024 * 1024);         // 4 MiB
  short* Vt      = (short*)(ws + (size_t)8 * 1024 * 1024);         // 4 MiB
  short* Wt      = (short*)(ws + (size_t)12 * 1024 * 1024);        // 192 KiB
  float* biasAll = (float*)(ws + (size_t)12 * 1024 * 1024 + 192 * 1024);  // 768 B
  // total workspace footprint: ~12.2 MiB (validated rounds 1/4/5)

  prep_weights<<<192, 256, 0, stream>>>(Wq, Wk, Wv, bq, bk, bv, Wt, biasAll);
  qkv_proj<<<1024, 384, 0, stream>>>(in, Wt, biasAll, Qb, Kb, Vt);
  hipMemsetAsync(d_out, 0, (size_t)out_size * sizeof(float), stream);
  attn_pool<<<1024, 256, 0, stream>>>(Qb, Kb, Vt, out);
}